// Round 1
// 93.231 us; speedup vs baseline: 1.0433x; 1.0433x over previous
//
#include <hip/hip_runtime.h>
#include <math.h>

#define H 512
#define W 512
#define TBINS 180
#define RBINS 360
#define NPIX (H*W)
#define NCELL (TBINS*RBINS)

#define THETA_MIN (-1.5707963267948966f)
#define T_BIN ((float)(3.141592653589793 / 179.0))
#define R_MIN (-724.0773439350246f)
#define R_BIN ((float)(2.0 * 724.0773439350246 / 359.0))
#define THR_VAR 100.0f
#define WSIG 6.0f          // window: tail mass < 2e-9, << 1.16e-2 budget (stable R4-R10)

#define NT 6               // rho tiles (64 cols each)
#define KB 80              // max gemm blocks per tile (grid-stride over full 32-chunks)
#define BCAP 32768
#define MPAD 192           // theta rows padded to 12 m-tiles of 16
#define PADC 32            // counts padded 128 B apart

typedef short v8s __attribute__((ext_vector_type(8)));
typedef float v4f __attribute__((ext_vector_type(4)));

__device__ __forceinline__ float phi_cdf(float z) {
    return 0.5f * erfcf(-0.70710678118654752f * z);
}
__device__ __forceinline__ unsigned short f2bf(float f) {   // RNE f32->bf16
    unsigned u = __float_as_uint(f);
    return (unsigned short)((u + 0x7FFF + ((u >> 16) & 1)) >> 16);
}
__device__ __forceinline__ float bf2f(unsigned short b) {
    return __uint_as_float(((unsigned)b) << 16);
}

// Faithful to reference incl. row_s quirk (residual uses img[clip(hi+dx), wi]).
// R11: conservative rsqrt prefilter (x1.01 headroom, err bound ~4e-4 << 1%);
// exact atanf/cosf/sinf recomputed only for surviving pixels -> record values
// bit-identical to the R10 kernel.
__global__ void prep_kernel(const float* __restrict__ img,
                            const float* __restrict__ mask,
                            int* __restrict__ counts,
                            float4* __restrict__ recs,
                            float* __restrict__ mvs,
                            float* __restrict__ out) {
    __shared__ int lcnt[NT], gbase[NT];
    int tid = threadIdx.x;
    int gid = blockIdx.x * blockDim.x + tid;
    if (gid < NCELL) out[gid] = 0.0f;        // fused d_out zeroing
    if (tid < NT) lcnt[tid] = 0;
    __syncthreads();

    int p = gid;
    int hi = p >> 9, wi = p & (W - 1);
    float mv = mask[p];

    int xm = max(hi - 1, 0), xp = min(hi + 1, H - 1);
    int ym = max(wi - 1, 0), yp = min(wi + 1, W - 1);
    const float* r0 = img + xm * W;
    const float* r1 = img + hi * W;
    const float* r2 = img + xp * W;
    float s00 = r0[ym], s01 = r0[wi], s02 = r0[yp];
    float s10 = r1[ym], s11 = r1[wi], s12 = r1[yp];
    float s20 = r2[ym], s21 = r2[wi], s22 = r2[yp];

    float alpha_s = (s20 + s21 + s22) - (s00 + s01 + s02);
    float beta_s  = (s02 + s12 + s22) - (s00 + s10 + s20);
    float gsum    = s00 + s01 + s02 + s10 + s11 + s12 + s20 + s21 + s22;

    float alpha = alpha_s * (1.0f / 6.0f) + 1e-6f;
    float beta  = beta_s  * (1.0f / 6.0f) + 1e-6f;
    float gamma = gsum * (1.0f / 9.0f);

    float cvals[3] = { s01, s11, s21 };
    float eps2 = 0.0f;
    #pragma unroll
    for (int ix = 0; ix < 3; ++ix) {
        float dx = (float)(ix - 1);
        float c = cvals[ix];
        #pragma unroll
        for (int iy = 0; iy < 3; ++iy) {
            float dy = (float)(iy - 1);
            float r = c - alpha * dy - beta * dx - gamma;
            eps2 += r * r;
        }
    }
    float noise_var = eps2 * (1.0f / 7.0f);
    float va = noise_var * (1.0f / 6.0f);
    float g2 = alpha * alpha + beta * beta;
    float var_theta = (beta * beta * va + alpha * alpha * va) / (g2 * g2);

    // ---- cheap conservative prefilter: no trig. ct=|a|/|g|, st=sgn(a)*b/|g| ----
    float x = (float)hi, y = (float)wi;
    float inv_g = rsqrtf(g2);
    float cta = fabsf(alpha) * inv_g;
    float sta = (alpha < 0.0f ? -beta : beta) * inv_g;
    float drho_a = -x * sta + y * cta;
    float var_rho_a = drho_a * drho_a * var_theta;
    bool maybe = (var_theta <= THR_VAR) && (var_rho_a <= THR_VAR * 1.01f) && (mv != 0.0f);

    int myNt[2] = { -1, -1 };
    int myPos[2];
    float4 rc;
    if (maybe) {
        // exact path (bit-identical to previous kernel's records)
        float theta = atanf(beta / alpha);
        float ct = cosf(theta), st = sinf(theta);
        float rho = x * ct + y * st;
        float drho = -x * st + y * ct;
        float var_rho = drho * drho * var_theta;
        if (var_rho <= THR_VAR) {
            float sig_t = sqrtf(var_theta + 1e-12f);
            float sig_r = sqrtf(var_rho + 1e-12f);
            float radr = WSIG * sig_r;
            int rlo = max((int)floorf((rho - radr - R_MIN) / R_BIN - 0.5f), 0);
            int rhi = min((int)ceilf((rho + radr - R_MIN) / R_BIN + 0.5f), RBINS - 1);
            if (rhi >= rlo) {
                rc.x = theta; rc.y = 1.0f / sig_t; rc.z = rho; rc.w = 1.0f / sig_r;
                int nt0 = rlo >> 6, nt1 = rhi >> 6;   // window <= 32 bins -> <= 2 tiles
                for (int nt = nt0; nt <= nt1; ++nt) {
                    int k = nt - nt0;
                    myNt[k] = nt;
                    myPos[k] = atomicAdd(&lcnt[nt], 1);
                }
            }
        }
    }
    __syncthreads();
    if (tid < NT) {
        int c = lcnt[tid];
        gbase[tid] = c ? atomicAdd(&counts[tid * PADC], c) : 0;
    }
    __syncthreads();
    #pragma unroll
    for (int k = 0; k < 2; ++k) {
        if (myNt[k] >= 0) {
            int pos = gbase[myNt[k]] + myPos[k];
            if (pos < BCAP) {
                recs[myNt[k] * BCAP + pos] = rc;
                mvs[myNt[k] * BCAP + pos] = mv;
            }
        }
    }
}

// GEMM M=192(pad) N=64/tile, grid-stride over FULL 32-record chunks (R11: no
// K-padding waste; idle blocks exit). Edge CDFs + diffs fused in registers:
// 16 threads/pixel, each owns a contiguous 16-slot strip (17 edges) -> EA/EB
// LDS round-trip and one barrier removed. Weight arithmetic bit-identical to
// R10 (same phi_cdf / diff / f2bf expressions). bf16 hi/lo split -> 3 MFMAs.
__global__ void __launch_bounds__(512)
gemm_kernel(const float4* __restrict__ recs,
            const float* __restrict__ mvs,
            const int* __restrict__ counts,
            float* __restrict__ out) {
    __shared__ __align__(16) unsigned short Ah[MPAD * 32], Al[MPAD * 32]; // [m][k]
    __shared__ __align__(16) unsigned short Bh[64 * 32],  Bl[64 * 32];    // [n][k]
    __shared__ float4 prec[32];
    __shared__ float  pmv[32];

    int nt = blockIdx.x % NT, kb = blockIdx.x / NT;
    int tid = threadIdx.x;
    int lane = tid & 63, wv = tid >> 6;
    int nsub = wv & 3, mhalf = wv >> 2;
    int c0 = nt * 64;
    int nbmax = min(63, RBINS - 1 - c0);

    int cn = min(counts[nt * PADC], BCAP);
    int nck = (cn + 31) >> 5;          // full 32-wide chunks
    if (kb >= nck) return;             // idle block (out pre-zeroed in prep)

    v4f zero = {0.f, 0.f, 0.f, 0.f};
    v4f acc[6];
    #pragma unroll
    for (int i = 0; i < 6; ++i) acc[i] = zero;

    const float4* rb = recs + (size_t)nt * BCAP;
    const float*  mb = mvs + (size_t)nt * BCAP;

    int pix = tid & 31, g = tid >> 5;  // 16 groups x 32 pixels

    for (int ck = kb; ck < nck; ck += KB) {
        int k0 = ck << 5;
        int k1 = min(k0 + 32, cn);
        if (ck != kb) __syncthreads();             // protect A/B tiles + prec
        if (tid < 32) {
            int idx = k0 + tid;
            float4 rc; rc.x = 0.f; rc.y = 0.f; rc.z = 0.f; rc.w = 0.f;
            float m = 0.f;
            if (idx < k1) { rc = rb[idx]; m = mb[idx]; }
            prec[tid] = rc; pmv[tid] = m;
        }
        __syncthreads();

        float4 rc = prec[pix];
        float m = pmv[pix];
        float v[17];
        if (g < 12) {
            // theta strip: slots [16g, 16g+16), edges [16g, 16g+16]
            int e0 = g << 4;
            if (rc.y != 0.0f) {
                float sigt = 1.0f / rc.y;
                int wx = max((int)floorf((rc.x - WSIG * sigt - THETA_MIN) / T_BIN - 0.5f), 0);
                int wy = min((int)ceilf((rc.x + WSIG * sigt - THETA_MIN) / T_BIN + 0.5f), TBINS - 1);
                #pragma unroll
                for (int i = 0; i <= 16; ++i) {
                    int e = e0 + i;
                    float val;
                    if (e < wx) val = 0.0f;
                    else if (e > wy + 1) val = 1.0f;
                    else {
                        float edge = THETA_MIN + ((float)e - 0.5f) * T_BIN;
                        val = phi_cdf((edge - rc.x) * rc.y);
                    }
                    v[i] = val;
                }
            } else {
                #pragma unroll
                for (int i = 0; i <= 16; ++i) v[i] = 0.0f;
            }
            int sb = e0 * 32 + pix;
            #pragma unroll
            for (int i = 0; i < 16; ++i) {
                float wt = (v[i + 1] - v[i]) * m;
                unsigned short hb = f2bf(wt);
                Ah[sb + i * 32] = hb;
                Al[sb + i * 32] = f2bf(wt - bf2f(hb));
            }
        } else {
            // rho strip: rows [16(g-12), +16), edges likewise
            int n0 = (g - 12) << 4;
            if (rc.y != 0.0f) {
                float sigr = 1.0f / rc.w;
                int wz = max((int)floorf((rc.z - WSIG * sigr - R_MIN) / R_BIN - 0.5f) - c0, 0);
                int ww = min((int)ceilf((rc.z + WSIG * sigr - R_MIN) / R_BIN + 0.5f) - c0, nbmax);
                #pragma unroll
                for (int i = 0; i <= 16; ++i) {
                    int n = n0 + i;
                    float val;
                    if (n < wz) val = 0.0f;
                    else if (n > ww + 1) val = 1.0f;
                    else {
                        float edge = R_MIN + ((float)(c0 + n) - 0.5f) * R_BIN;
                        val = phi_cdf((edge - rc.z) * rc.w);
                    }
                    v[i] = val;
                }
            } else {
                #pragma unroll
                for (int i = 0; i <= 16; ++i) v[i] = 0.0f;
            }
            int sb = n0 * 32 + pix;
            #pragma unroll
            for (int i = 0; i < 16; ++i) {
                float wr = v[i + 1] - v[i];
                unsigned short hb = f2bf(wr);
                Bh[sb + i * 32] = hb;
                Bl[sb + i * 32] = f2bf(wr - bf2f(hb));
            }
        }
        __syncthreads();

        int kq = (lane >> 4) * 8;
        int mr = lane & 15;
        v8s bh = *((__shared__ v8s*)&Bh[(nsub * 16 + mr) * 32 + kq]);
        v8s bl = *((__shared__ v8s*)&Bl[(nsub * 16 + mr) * 32 + kq]);
        #pragma unroll
        for (int mt = 0; mt < 6; ++mt) {
            int mbase = (mhalf * 6 + mt) * 16;
            v8s ah = *((__shared__ v8s*)&Ah[(mbase + mr) * 32 + kq]);
            v8s al = *((__shared__ v8s*)&Al[(mbase + mr) * 32 + kq]);
            acc[mt] = __builtin_amdgcn_mfma_f32_16x16x32_bf16(ah, bh, acc[mt], 0, 0, 0);
            acc[mt] = __builtin_amdgcn_mfma_f32_16x16x32_bf16(ah, bl, acc[mt], 0, 0, 0);
            acc[mt] = __builtin_amdgcn_mfma_f32_16x16x32_bf16(al, bh, acc[mt], 0, 0, 0);
        }
    }

    // drain: C/D col=lane&15 (n), row=(lane>>4)*4+reg (m)  [verified R6-R10]
    int gcol = c0 + nsub * 16 + (lane & 15);
    if (gcol < RBINS) {
        int rq = (lane >> 4) * 4;
        #pragma unroll
        for (int mt = 0; mt < 6; ++mt) {
            int rbase = (mhalf * 6 + mt) * 16 + rq;
            #pragma unroll
            for (int r = 0; r < 4; ++r) {
                int row = rbase + r;
                float v = acc[mt][r];
                if (row < TBINS && v != 0.0f)
                    atomicAdd(&out[row * RBINS + gcol], v);
            }
        }
    }
}

extern "C" void kernel_launch(void* const* d_in, const int* in_sizes, int n_in,
                              void* d_out, int out_size, void* d_ws, size_t ws_size,
                              hipStream_t stream) {
    const float* img  = (const float*)d_in[0];
    const float* mask = (const float*)d_in[1];
    float* out = (float*)d_out;

    // ws: counts @0 (1 KB) ; recs @1024 (3.15 MB) ; mvs (786 KB)  (~4 MB)
    char* ws = (char*)d_ws;
    int*    counts = (int*)ws;
    float4* recs   = (float4*)(ws + 1024);
    float*  mvs    = (float*)(ws + 1024 + (size_t)NT * BCAP * 16);

    hipMemsetAsync(counts, 0, NT * PADC * sizeof(int), stream);
    prep_kernel<<<NPIX / 256, 256, 0, stream>>>(img, mask, counts, recs, mvs, out);
    gemm_kernel<<<NT * KB, 512, 0, stream>>>(recs, mvs, counts, out);
}

// Round 2
// 83.791 us; speedup vs baseline: 1.1609x; 1.1127x over previous
//
#include <hip/hip_runtime.h>
#include <math.h>

#define H 512
#define W 512
#define TBINS 180
#define RBINS 360
#define NPIX (H*W)
#define NCELL (TBINS*RBINS)

#define THETA_MIN (-1.5707963267948966f)
#define T_BIN ((float)(3.141592653589793 / 179.0))
#define R_MIN (-724.0773439350246f)
#define R_BIN ((float)(2.0 * 724.0773439350246 / 359.0))
#define THR_VAR 100.0f
#define WSIG 6.0f          // window: tail mass < 2e-9, << 1.16e-2 budget (stable R4-R10)

#define NT 6               // rho tiles (64 cols each)
#define KB 80              // max gemm blocks per tile (grid-stride over full 32-chunks)
#define NBLK 1024          // prep blocks = record segments per tile
#define SCAP 256           // per-(block,tile) segment capacity (256 pix/block -> exact-safe)
#define MPAD 192           // theta rows padded to 12 m-tiles of 16

typedef short v8s __attribute__((ext_vector_type(8)));
typedef float v4f __attribute__((ext_vector_type(4)));

__device__ __forceinline__ float phi_cdf(float z) {
    return 0.5f * erfcf(-0.70710678118654752f * z);
}
__device__ __forceinline__ unsigned short f2bf(float f) {   // RNE f32->bf16
    unsigned u = __float_as_uint(f);
    return (unsigned short)((u + 0x7FFF + ((u >> 16) & 1)) >> 16);
}
__device__ __forceinline__ float bf2f(unsigned short b) {
    return __uint_as_float(((unsigned)b) << 16);
}

// Faithful to reference incl. row_s quirk (residual uses img[clip(hi+dx), wi]).
// R12: per-block segmented record store (cblk written unconditionally every
// iteration) -> no global counter, no counts memset dispatch. Record values
// bit-identical to R11; only packing order changes.
__global__ void prep_kernel(const float* __restrict__ img,
                            const float* __restrict__ mask,
                            int* __restrict__ cblk,
                            float4* __restrict__ recs,
                            float* __restrict__ mvs,
                            float* __restrict__ out) {
    __shared__ int lcnt[NT];
    int tid = threadIdx.x;
    int b = blockIdx.x;
    int gid = b * blockDim.x + tid;
    if (gid < NCELL) out[gid] = 0.0f;        // fused d_out zeroing
    if (tid < NT) lcnt[tid] = 0;
    __syncthreads();

    int p = gid;
    int hi = p >> 9, wi = p & (W - 1);
    float mv = mask[p];

    int xm = max(hi - 1, 0), xp = min(hi + 1, H - 1);
    int ym = max(wi - 1, 0), yp = min(wi + 1, W - 1);
    const float* r0 = img + xm * W;
    const float* r1 = img + hi * W;
    const float* r2 = img + xp * W;
    float s00 = r0[ym], s01 = r0[wi], s02 = r0[yp];
    float s10 = r1[ym], s11 = r1[wi], s12 = r1[yp];
    float s20 = r2[ym], s21 = r2[wi], s22 = r2[yp];

    float alpha_s = (s20 + s21 + s22) - (s00 + s01 + s02);
    float beta_s  = (s02 + s12 + s22) - (s00 + s10 + s20);
    float gsum    = s00 + s01 + s02 + s10 + s11 + s12 + s20 + s21 + s22;

    float alpha = alpha_s * (1.0f / 6.0f) + 1e-6f;
    float beta  = beta_s  * (1.0f / 6.0f) + 1e-6f;
    float gamma = gsum * (1.0f / 9.0f);

    float cvals[3] = { s01, s11, s21 };
    float eps2 = 0.0f;
    #pragma unroll
    for (int ix = 0; ix < 3; ++ix) {
        float dx = (float)(ix - 1);
        float c = cvals[ix];
        #pragma unroll
        for (int iy = 0; iy < 3; ++iy) {
            float dy = (float)(iy - 1);
            float r = c - alpha * dy - beta * dx - gamma;
            eps2 += r * r;
        }
    }
    float noise_var = eps2 * (1.0f / 7.0f);
    float va = noise_var * (1.0f / 6.0f);
    float g2 = alpha * alpha + beta * beta;
    float var_theta = (beta * beta * va + alpha * alpha * va) / (g2 * g2);

    // ---- cheap conservative prefilter: no trig. ct=|a|/|g|, st=sgn(a)*b/|g| ----
    float x = (float)hi, y = (float)wi;
    float inv_g = rsqrtf(g2);
    float cta = fabsf(alpha) * inv_g;
    float sta = (alpha < 0.0f ? -beta : beta) * inv_g;
    float drho_a = -x * sta + y * cta;
    float var_rho_a = drho_a * drho_a * var_theta;
    bool maybe = (var_theta <= THR_VAR) && (var_rho_a <= THR_VAR * 1.01f) && (mv != 0.0f);

    int myNt[2] = { -1, -1 };
    int myPos[2];
    float4 rc;
    if (maybe) {
        // exact path (bit-identical to previous kernel's records)
        float theta = atanf(beta / alpha);
        float ct = cosf(theta), st = sinf(theta);
        float rho = x * ct + y * st;
        float drho = -x * st + y * ct;
        float var_rho = drho * drho * var_theta;
        if (var_rho <= THR_VAR) {
            float sig_t = sqrtf(var_theta + 1e-12f);
            float sig_r = sqrtf(var_rho + 1e-12f);
            float radr = WSIG * sig_r;
            int rlo = max((int)floorf((rho - radr - R_MIN) / R_BIN - 0.5f), 0);
            int rhi = min((int)ceilf((rho + radr - R_MIN) / R_BIN + 0.5f), RBINS - 1);
            if (rhi >= rlo) {
                rc.x = theta; rc.y = 1.0f / sig_t; rc.z = rho; rc.w = 1.0f / sig_r;
                int nt0 = rlo >> 6, nt1 = rhi >> 6;   // window <= 32 bins -> <= 2 tiles
                for (int nt = nt0; nt <= nt1; ++nt) {
                    int k = nt - nt0;
                    myNt[k] = nt;
                    myPos[k] = atomicAdd(&lcnt[nt], 1);
                }
            }
        }
    }
    __syncthreads();
    // per-tile per-block counts: unconditional store -> no zero-init dependency
    if (tid < NT) cblk[tid * NBLK + b] = lcnt[tid];
    #pragma unroll
    for (int k = 0; k < 2; ++k) {
        if (myNt[k] >= 0) {
            int idx = (myNt[k] * NBLK + b) * SCAP + myPos[k];
            recs[idx] = rc;
            mvs[idx]  = mv;
        }
    }
}

// GEMM M=192(pad) N=64/tile, grid-stride over FULL 32-record chunks. R12:
// packed record view reconstructed via LDS prefix scan of the 1024 per-block
// counts (3 barriers, wave-shfl) + branchless binary search per loader lane.
// Edge CDFs + diffs fused in registers (16 threads/pixel, 17-edge strips).
// Weight arithmetic bit-identical to R10/R11. bf16 hi/lo split -> 3 MFMAs.
__global__ void __launch_bounds__(512)
gemm_kernel(const float4* __restrict__ recs,
            const float* __restrict__ mvs,
            const int* __restrict__ cblk,
            float* __restrict__ out) {
    __shared__ __align__(16) unsigned short Ah[MPAD * 32], Al[MPAD * 32]; // [m][k]
    __shared__ __align__(16) unsigned short Bh[64 * 32],  Bl[64 * 32];    // [n][k]
    __shared__ float4 prec[32];
    __shared__ float  pmv[32];
    __shared__ int    pref[NBLK];       // inclusive prefix of per-block counts
    __shared__ int    wsum[8], woff[8];

    int nt = blockIdx.x % NT, kb = blockIdx.x / NT;
    int tid = threadIdx.x;
    int lane = tid & 63, wv = tid >> 6;
    int nsub = wv & 3, mhalf = wv >> 2;
    int c0 = nt * 64;
    int nbmax = min(63, RBINS - 1 - c0);

    // ---- prefix scan: 1024 counts, 2 per thread, wave shfl + 8-wave fixup ----
    const int* cb = cblk + nt * NBLK;
    int a0 = cb[2 * tid], a1 = cb[2 * tid + 1];
    int s = a0 + a1;
    #pragma unroll
    for (int d = 1; d < 64; d <<= 1) {
        int u = __shfl_up(s, d);
        if (lane >= d) s += u;
    }
    if (lane == 63) wsum[wv] = s;
    __syncthreads();
    if (tid == 0) {
        int r = 0;
        #pragma unroll
        for (int i = 0; i < 8; ++i) { woff[i] = r; r += wsum[i]; }
    }
    __syncthreads();
    int base = woff[wv] + s;            // inclusive through element 2*tid+1
    pref[2 * tid]     = base - a1;
    pref[2 * tid + 1] = base;
    __syncthreads();

    int cn = pref[NBLK - 1];
    int nck = (cn + 31) >> 5;          // full 32-wide chunks
    if (kb >= nck) return;             // idle block (out pre-zeroed in prep)

    v4f zero = {0.f, 0.f, 0.f, 0.f};
    v4f acc[6];
    #pragma unroll
    for (int i = 0; i < 6; ++i) acc[i] = zero;

    const float4* rb = recs + (size_t)nt * NBLK * SCAP;
    const float*  mb = mvs + (size_t)nt * NBLK * SCAP;

    int pix = tid & 31, g = tid >> 5;  // 16 groups x 32 pixels

    for (int ck = kb; ck < nck; ck += KB) {
        int k0 = ck << 5;
        int k1 = min(k0 + 32, cn);
        if (ck != kb) __syncthreads();             // protect A/B tiles + prec
        if (tid < 32) {
            int r = k0 + tid;
            float4 rc; rc.x = 0.f; rc.y = 0.f; rc.z = 0.f; rc.w = 0.f;
            float m = 0.f;
            if (r < k1) {
                // first segment b with pref[b] > r  (count entries <= r)
                int pos = 0;
                #pragma unroll
                for (int st = 512; st >= 1; st >>= 1)
                    if (pos + st <= NBLK && pref[pos + st - 1] <= r) pos += st;
                int off = r - (pos ? pref[pos - 1] : 0);
                int idx = pos * SCAP + off;
                rc = rb[idx]; m = mb[idx];
            }
            prec[tid] = rc; pmv[tid] = m;
        }
        __syncthreads();

        float4 rc = prec[pix];
        float m = pmv[pix];
        float v[17];
        if (g < 12) {
            // theta strip: slots [16g, 16g+16), edges [16g, 16g+16]
            int e0 = g << 4;
            if (rc.y != 0.0f) {
                float sigt = 1.0f / rc.y;
                int wx = max((int)floorf((rc.x - WSIG * sigt - THETA_MIN) / T_BIN - 0.5f), 0);
                int wy = min((int)ceilf((rc.x + WSIG * sigt - THETA_MIN) / T_BIN + 0.5f), TBINS - 1);
                #pragma unroll
                for (int i = 0; i <= 16; ++i) {
                    int e = e0 + i;
                    float val;
                    if (e < wx) val = 0.0f;
                    else if (e > wy + 1) val = 1.0f;
                    else {
                        float edge = THETA_MIN + ((float)e - 0.5f) * T_BIN;
                        val = phi_cdf((edge - rc.x) * rc.y);
                    }
                    v[i] = val;
                }
            } else {
                #pragma unroll
                for (int i = 0; i <= 16; ++i) v[i] = 0.0f;
            }
            int sb = e0 * 32 + pix;
            #pragma unroll
            for (int i = 0; i < 16; ++i) {
                float wt = (v[i + 1] - v[i]) * m;
                unsigned short hb = f2bf(wt);
                Ah[sb + i * 32] = hb;
                Al[sb + i * 32] = f2bf(wt - bf2f(hb));
            }
        } else {
            // rho strip: rows [16(g-12), +16), edges likewise
            int n0 = (g - 12) << 4;
            if (rc.y != 0.0f) {
                float sigr = 1.0f / rc.w;
                int wz = max((int)floorf((rc.z - WSIG * sigr - R_MIN) / R_BIN - 0.5f) - c0, 0);
                int ww = min((int)ceilf((rc.z + WSIG * sigr - R_MIN) / R_BIN + 0.5f) - c0, nbmax);
                #pragma unroll
                for (int i = 0; i <= 16; ++i) {
                    int n = n0 + i;
                    float val;
                    if (n < wz) val = 0.0f;
                    else if (n > ww + 1) val = 1.0f;
                    else {
                        float edge = R_MIN + ((float)(c0 + n) - 0.5f) * R_BIN;
                        val = phi_cdf((edge - rc.z) * rc.w);
                    }
                    v[i] = val;
                }
            } else {
                #pragma unroll
                for (int i = 0; i <= 16; ++i) v[i] = 0.0f;
            }
            int sb = n0 * 32 + pix;
            #pragma unroll
            for (int i = 0; i < 16; ++i) {
                float wr = v[i + 1] - v[i];
                unsigned short hb = f2bf(wr);
                Bh[sb + i * 32] = hb;
                Bl[sb + i * 32] = f2bf(wr - bf2f(hb));
            }
        }
        __syncthreads();

        int kq = (lane >> 4) * 8;
        int mr = lane & 15;
        v8s bh = *((__shared__ v8s*)&Bh[(nsub * 16 + mr) * 32 + kq]);
        v8s bl = *((__shared__ v8s*)&Bl[(nsub * 16 + mr) * 32 + kq]);
        #pragma unroll
        for (int mt = 0; mt < 6; ++mt) {
            int mbase = (mhalf * 6 + mt) * 16;
            v8s ah = *((__shared__ v8s*)&Ah[(mbase + mr) * 32 + kq]);
            v8s al = *((__shared__ v8s*)&Al[(mbase + mr) * 32 + kq]);
            acc[mt] = __builtin_amdgcn_mfma_f32_16x16x32_bf16(ah, bh, acc[mt], 0, 0, 0);
            acc[mt] = __builtin_amdgcn_mfma_f32_16x16x32_bf16(ah, bl, acc[mt], 0, 0, 0);
            acc[mt] = __builtin_amdgcn_mfma_f32_16x16x32_bf16(al, bh, acc[mt], 0, 0, 0);
        }
    }

    // drain: C/D col=lane&15 (n), row=(lane>>4)*4+reg (m)  [verified R6-R10]
    int gcol = c0 + nsub * 16 + (lane & 15);
    if (gcol < RBINS) {
        int rq = (lane >> 4) * 4;
        #pragma unroll
        for (int mt = 0; mt < 6; ++mt) {
            int rbase = (mhalf * 6 + mt) * 16 + rq;
            #pragma unroll
            for (int r = 0; r < 4; ++r) {
                int row = rbase + r;
                float v = acc[mt][r];
                if (row < TBINS && v != 0.0f)
                    atomicAdd(&out[row * RBINS + gcol], v);
            }
        }
    }
}

extern "C" void kernel_launch(void* const* d_in, const int* in_sizes, int n_in,
                              void* d_out, int out_size, void* d_ws, size_t ws_size,
                              hipStream_t stream) {
    const float* img  = (const float*)d_in[0];
    const float* mask = (const float*)d_in[1];
    float* out = (float*)d_out;

    // ws: cblk @0 (24.6 KB) ; recs @32768 (25.2 MB) ; mvs (6.3 MB)  (~31.5 MB)
    char* ws = (char*)d_ws;
    int*    cblk = (int*)ws;
    float4* recs = (float4*)(ws + 32768);
    float*  mvs  = (float*)(ws + 32768 + (size_t)NT * NBLK * SCAP * 16);

    // no memset: cblk is written unconditionally by every prep block
    prep_kernel<<<NPIX / 256, 256, 0, stream>>>(img, mask, cblk, recs, mvs, out);
    gemm_kernel<<<NT * KB, 512, 0, stream>>>(recs, mvs, cblk, out);
}